// Round 1
// baseline (244.059 us; speedup 1.0000x reference)
//
#include <hip/hip_runtime.h>
#include <math.h>

// MixEHR-Seed update. Shapes fixed by the benchmark:
constexpr int Bc = 64;      // batch
constexpr int Vc = 8000;    // vocab
constexpr int Kc = 50;      // topics
// constants from reference
// ETA=BETA=MU=0.1, PI_INIT=0.7, MINI=1e-6, C_TOTAL=1e7

// ws float layout:
// [0..49]    exp_n_sum[k]
// [50..99]   exp_s_sum[k]
// [100..149] gamma_sr_sum[k]   (atomic f32)
// [150]      exp_q_z           (atomic f32)
// [151]      batch_C           (atomic int, exact)
// [152]      S seed-word count (atomic int, exact)
// [160..209] exp_s_sum_new[k]

__global__ __launch_bounds__(256) void k1_pre(const int* __restrict__ bow,
    const float* __restrict__ seeds, const float* __restrict__ exp_n,
    const float* __restrict__ exp_s, float* __restrict__ ws)
{
    __shared__ float redf[256];
    __shared__ int   redi[256];
    const int t = threadIdx.x;
    const int blk = blockIdx.x;
    if (blk < Kc) {
        // column sums over v for topic k=blk
        float sn = 0.f, ss = 0.f;
        for (int v = t; v < Vc; v += 256) {
            sn += exp_n[v*Kc + blk];
            ss += exp_s[v*Kc + blk];
        }
        redf[t] = sn; __syncthreads();
        for (int s = 128; s > 0; s >>= 1) { if (t < s) redf[t] += redf[t+s]; __syncthreads(); }
        if (t == 0) ws[blk] = redf[0];
        __syncthreads();
        redf[t] = ss; __syncthreads();
        for (int s = 128; s > 0; s >>= 1) { if (t < s) redf[t] += redf[t+s]; __syncthreads(); }
        if (t == 0) ws[Kc + blk] = redf[0];
    } else if (blk < Kc + 32) {
        // batch_C = sum(bow), exact in int
        int acc = 0;
        for (int i = (blk - Kc)*256 + t; i < Bc*Vc; i += 32*256) acc += bow[i];
        redi[t] = acc; __syncthreads();
        for (int s = 128; s > 0; s >>= 1) { if (t < s) redi[t] += redi[t+s]; __syncthreads(); }
        if (t == 0) atomicAdd((int*)ws + 151, redi[0]);
    } else {
        // S = number of seed words
        int cnt = 0;
        for (int v = (blk - Kc - 32)*256 + t; v < Vc; v += 8*256) {
            const float* row = seeds + v*Kc;
            int any = 0;
            for (int k = 0; k < Kc; ++k) any |= (row[k] != 0.f);
            cnt += any;
        }
        redi[t] = cnt; __syncthreads();
        for (int s = 128; s > 0; s >>= 1) { if (t < s) redi[t] += redi[t+s]; __syncthreads(); }
        if (t == 0) atomicAdd((int*)ws + 152, redi[0]);
    }
}

// Main gamma kernel: one wave handles a set of v's; lanes 0..49 = topics.
__global__ __launch_bounds__(512) void k2_main(
    const int* __restrict__ bow, const int* __restrict__ bidx,
    const float* __restrict__ seeds, const float* __restrict__ exp_m,
    const float* __restrict__ exp_n, const float* __restrict__ exp_s,
    const float* __restrict__ pi, float* __restrict__ ws,
    float* __restrict__ out)
{
    float* out_m = out;                       // [B*K] accumulates temp_exp_m (pre-zeroed)
    float* out_n = out + Bc*Kc;               // temp_exp_n staging (finalized in k3)
    float* out_s = out + Bc*Kc + Vc*Kc;       // temp_exp_s staging

    __shared__ float lds_m[Bc*Kc];            // block-local temp_exp_m
    __shared__ float lds_theta[Bc*Kc];        // theta[b][k] = exp_m[bidx[b]][k] + ETA
    __shared__ float lds_srsum[Kc];
    __shared__ float lds_qz;

    const int t = threadIdx.x;
    for (int i = t; i < Bc*Kc; i += 512) lds_m[i] = 0.f;
    if (t < Kc) lds_srsum[t] = 0.f;
    if (t == 0) lds_qz = 0.f;
    for (int i = t; i < Bc*Kc; i += 512) {
        int b = i / Kc;
        lds_theta[i] = exp_m[bidx[b]*Kc + (i - b*Kc)] + 0.1f;
    }
    __syncthreads();

    const int lane = t & 63;
    const int wid  = t >> 6;
    const int gw   = blockIdx.x * 8 + wid;
    const int nw   = gridDim.x * 8;
    const int k    = lane;
    const bool kval = (k < Kc);

    const float S_f      = (float)(((const int*)ws)[152]);
    const float mu_sum   = 0.1f * S_f;
    const float beta_sum = 0.1f * (float)Vc;
    float pi_k = 0.f, omp_k = 0.f, sden_inv = 0.f, rden_inv = 0.f;
    if (kval) {
        pi_k = pi[k];
        omp_k = 1.f - pi_k;
        sden_inv = 1.f / (mu_sum + ws[Kc + k]);
        rden_inv = 1.f / (beta_sum + ws[k]);
    }

    float acc_sr = 0.f;   // gamma_sr_sum partial (per lane k)
    float acc_qz = 0.f;   // exp_q_z partial

    for (int v = gw; v < Vc; v += nw) {
        float seeds_vk = 0.f, es = 0.f, en = 0.f;
        if (kval) {
            seeds_vk = seeds[v*Kc + k];
            es = exp_s[v*Kc + k];
            en = exp_n[v*Kc + k];
        }
        const float st = (0.1f + es) * sden_inv;   // seed_topic_term
        const float rt = (0.1f + en) * rden_inv;   // reg_topic_term
        const bool seed_word = (__ballot(seeds_vk != 0.f) != 0ULL);
        const float bow_lane = (float)bow[lane*Vc + v];   // lane = b

        float acc_n = 0.f, acc_s = 0.f;

        for (int b = 0; b < Bc; ++b) {
            const float bw = __shfl(bow_lane, b);
            if (bw == 0.f) continue;               // wave-uniform skip
            const float th = lds_theta[b*Kc + (kval ? k : 0)];
            float ss = seeds_vk * th * st * pi_k;
            float sr = seeds_vk * th * rt * omp_k;
            float rr = (1.f - seeds_vk) * th * rt; // ==0 for invalid lanes (rt==0)
            float ssum = ss + sr;
            float rsum = rr;
            for (int off = 32; off > 0; off >>= 1) {
                ssum += __shfl_xor(ssum, off);
                rsum += __shfl_xor(rsum, off);
            }
            const float inv_s = __builtin_amdgcn_rcpf(ssum + 1e-6f);
            const float inv_r = __builtin_amdgcn_rcpf(rsum + 1e-6f);
            const float ssn = ss * inv_s;
            const float srn = sr * inv_s;
            const float rrn = rr * inv_r;
            const float g = seed_word ? (pi_k*ssn + omp_k*(srn + rrn)) : rrn;
            acc_n  += (srn + rrn) * bw;
            acc_s  += ssn * bw;
            acc_sr += srn;
            acc_qz += g * __logf(g + 1e-6f);
            if (kval) atomicAdd(&lds_m[b*Kc + k], g * bw);
        }
        if (kval) {
            out_n[v*Kc + k] = acc_n;
            out_s[v*Kc + k] = acc_s;
        }
    }

    if (kval) atomicAdd(&lds_srsum[k], acc_sr);
    for (int off = 32; off > 0; off >>= 1) acc_qz += __shfl_xor(acc_qz, off);
    if (lane == 0) atomicAdd(&lds_qz, acc_qz);
    __syncthreads();

    for (int i = t; i < Bc*Kc; i += 512) {
        float vtm = lds_m[i];
        if (vtm != 0.f) atomicAdd(&out_m[i], vtm);
    }
    if (t < Kc) atomicAdd(&ws[100 + t], lds_srsum[t]);
    if (t == 0) atomicAdd(&ws[150], lds_qz);
}

__global__ __launch_bounds__(256) void k3_fin(
    const float* __restrict__ exp_m, const float* __restrict__ exp_n,
    const float* __restrict__ exp_s, const int* __restrict__ bidx,
    const int* __restrict__ itern_p, float* __restrict__ out,
    float* __restrict__ ws)
{
    const int t = threadIdx.x, blk = blockIdx.x;
    int ii = itern_p[0];
    // robust to the scalar arriving as int32 or float32 bits
    float itern = (ii >= 0 && ii < 1000000) ? (float)ii : __int_as_float(ii);
    const float rho = 1.f / powf(itern + 5.f, 0.9f);
    const float omr = 1.f - rho;
    const float bC  = (float)(((const int*)ws)[151]);
    const float scale = 1e7f / bC;
    float* out_m = out;
    float* out_n = out + Bc*Kc;
    float* out_s = out + Bc*Kc + Vc*Kc;

    if (blk < Kc) {
        const int k = blk;
        float acc = 0.f;
        for (int v = t; v < Vc; v += 256) {
            int i = v*Kc + k;
            out_n[i] = omr*exp_n[i] + rho*scale*out_n[i];
            float snew = omr*exp_s[i] + rho*scale*out_s[i];
            out_s[i] = snew;
            acc += snew;
        }
        __shared__ float redf[256];
        redf[t] = acc; __syncthreads();
        for (int s = 128; s > 0; s >>= 1) { if (t < s) redf[t] += redf[t+s]; __syncthreads(); }
        if (t == 0) ws[160 + k] = redf[0];   // exp_s_sum_new[k]
    } else {
        for (int i = t; i < Bc*Kc; i += 256) {
            int b = i / Kc;
            out_m[i] = omr*exp_m[bidx[b]*Kc + (i - b*Kc)] + rho*out_m[i];
        }
        if (t == 0) out[Bc*Kc + 2*Vc*Kc + Kc] = ws[150];   // exp_q_z
    }
}

__global__ void k4_pi(const float* __restrict__ ws, float* __restrict__ out) {
    int k = threadIdx.x;
    if (k < Kc) {
        float ssn = ws[160 + k];
        float srs = ws[100 + k];
        float p = ssn / (ssn + srs + 1e-6f);
        out[Bc*Kc + 2*Vc*Kc + k] = (p > 0.1f) ? p : 0.7f;
    }
}

extern "C" void kernel_launch(void* const* d_in, const int* in_sizes, int n_in,
                              void* d_out, int out_size, void* d_ws, size_t ws_size,
                              hipStream_t stream)
{
    const int*   bow    = (const int*)d_in[0];
    const int*   bidx   = (const int*)d_in[1];
    const float* seeds  = (const float*)d_in[2];
    const float* exp_m  = (const float*)d_in[3];
    const float* exp_n  = (const float*)d_in[4];
    const float* exp_s  = (const float*)d_in[5];
    const float* pi     = (const float*)d_in[6];
    const int*   iter_n = (const int*)d_in[7];
    float* out = (float*)d_out;
    float* ws  = (float*)d_ws;

    size_t zbytes = 1024;
    if (ws_size < zbytes) zbytes = ws_size;
    hipMemsetAsync(d_ws, 0, zbytes, stream);                      // accumulators
    hipMemsetAsync(d_out, 0, Bc*Kc*sizeof(float), stream);        // temp_exp_m region

    k1_pre<<<Kc + 32 + 8, 256, 0, stream>>>(bow, seeds, exp_n, exp_s, ws);
    k2_main<<<256, 512, 0, stream>>>(bow, bidx, seeds, exp_m, exp_n, exp_s, pi, ws, out);
    k3_fin<<<Kc + 1, 256, 0, stream>>>(exp_m, exp_n, exp_s, bidx, iter_n, out, ws);
    k4_pi<<<1, 64, 0, stream>>>(ws, out);
}